// Round 7
// baseline (849.684 us; speedup 1.0000x reference)
//
#include <hip/hip_runtime.h>

// Problem constants (from reference)
#define Bsz 16
#define Cc  256
#define Ll  4096
#define Pp  100
#define Qq  20
#define PQ  (Pp * Qq)     // 2000

typedef float f32x4 __attribute__((ext_vector_type(4)));

// ---------------------------------------------------------------------------
// NUMERICS CONTRACT (bit-exact vs numpy fp32 reference, validated R2/R4-R6):
//   a[b,p,l]: chain c=0..255 of a = fmaf(X[b,c,l], proj[p,c], a)      [fp32]
//   thr[p,q] = fadd(mn, fmul(fsub(mx,mn), fdiv(q+1, 21)))             [fp32,
//              separate roundings, no contraction]
//   set = (a < thr); cdf = popcount/4096 (exact dyadic fp32 atomics)
//
// R7 structure: the fused kernel's 16 KB-strided store stream ran at ~2.2-2.4
// TB/s (channel-aliasing theory: per-block stores differ only in addr bits
// >=14). Split into:
//   K1 csf_proj   — GEMM a[b,p,l] -> ws (26 MB), VALU-bound, ~30 us
//   K2 csf_expand — block (b,p) writes its 20 rows as ONE 320 KB contiguous
//                   stream (like the 6.26 TB/s fill), ~90 us target
// ---------------------------------------------------------------------------

// K1: grid (NLT1=4, NPG1=4, Bsz). Block 256 = 4 waves; wave wv covers l-chunk
// lt*1024 + wv*256 (lane owns 4 consecutive l); 25 p's per block.
#define K1_PPB 25
__global__ __launch_bounds__(256) void csf_proj(
    const float* __restrict__ X,
    const float* __restrict__ proj,
    float* __restrict__ a_out) {   // [B][P][L]
    const int lt = blockIdx.x;     // 0..3
    const int pg = blockIdx.y;     // 0..3
    const int b  = blockIdx.z;     // 0..15
    const int tid  = threadIdx.x;
    const int wv   = tid >> 6;
    const int lane = tid & 63;
    const int l0   = lt * 1024 + wv * 256 + lane * 4;
    const int p0   = __builtin_amdgcn_readfirstlane(pg * K1_PPB);

    const float* Xb = X + (size_t)b * Cc * Ll + l0;   // c-th element at +c*Ll
    const float* pj = proj + (size_t)p0 * Cc;         // wave-uniform rows

    float acc[K1_PPB][4];
#pragma unroll
    for (int i = 0; i < K1_PPB; i++)
#pragma unroll
        for (int k = 0; k < 4; k++) acc[i][k] = 0.0f;

    // fp32 FMA chains, c strictly ascending per accumulator (numpy order).
#pragma unroll 8
    for (int c = 0; c < Cc; c++) {
        const f32x4 x = *(const f32x4*)(Xb + (size_t)c * Ll);
#pragma unroll
        for (int i = 0; i < K1_PPB; i++) {
            const float w = pj[(size_t)i * Cc + c];
            acc[i][0] = __builtin_fmaf(x.x, w, acc[i][0]);
            acc[i][1] = __builtin_fmaf(x.y, w, acc[i][1]);
            acc[i][2] = __builtin_fmaf(x.z, w, acc[i][2]);
            acc[i][3] = __builtin_fmaf(x.w, w, acc[i][3]);
        }
    }

    float* ao = a_out + ((size_t)b * Pp + p0) * Ll + l0;
#pragma unroll
    for (int i = 0; i < K1_PPB; i++) {
        f32x4 v;
        v.x = acc[i][0]; v.y = acc[i][1]; v.z = acc[i][2]; v.w = acc[i][3];
        *(f32x4*)(ao + (size_t)i * Ll) = v;   // cached: K2 re-reads soon
    }
}

// K2: grid (Pp, Bsz) = 1600 blocks. Block (b,p) = 256 thr = 4 waves; wave wv
// owns row-quarter [wv*1024, +1024) (lane l = wv*1024 + k*256 + lane*4).
// q ascending -> the block emits 20 rows = 320 KB FULLY CONTIGUOUS.
__global__ __launch_bounds__(256) void csf_expand(
    const float* __restrict__ a_in,
    const float* __restrict__ mn,
    const float* __restrict__ mx,
    float* __restrict__ cdf,       // zeroed before launch
    float* __restrict__ set_out) {
    const int p = blockIdx.x;      // 0..99
    const int b = blockIdx.y;      // 0..15
    const int tid  = threadIdx.x;
    const int wv   = tid >> 6;
    const int lane = tid & 63;

    const float* ar = a_in + ((size_t)b * Pp + p) * Ll + wv * 1024 + lane * 4;
    f32x4 av[4];
#pragma unroll
    for (int k = 0; k < 4; k++) av[k] = *(const f32x4*)(ar + k * 256);

    const float mnp = mn[p];
    const float mxp = mx[p];
    const float d = __fsub_rn(mxp, mnp);              // fl(mx-mn)

    float* ob = set_out + ((size_t)b * PQ + (size_t)p * Qq) * Ll
              + wv * 1024 + lane * 4;
    const bool lane0 = (lane == 0);

#pragma unroll 1
    for (int q = 0; q < Qq; q++) {
        const float fr  = __fdiv_rn((float)(q + 1), 21.0f);      // fl((q+1)/21)
        const float thr = __fadd_rn(mnp, __fmul_rn(d, fr));      // separate rnd
        float* orow = ob + (size_t)q * Ll;
        int cnt = 0;
#pragma unroll
        for (int k = 0; k < 4; k++) {
            const bool b0 = av[k].x < thr;
            const bool b1 = av[k].y < thr;
            const bool b2 = av[k].z < thr;
            const bool b3 = av[k].w < thr;
            f32x4 o;
            o.x = b0 ? 1.0f : 0.0f;
            o.y = b1 ? 1.0f : 0.0f;
            o.z = b2 ? 1.0f : 0.0f;
            o.w = b3 ? 1.0f : 0.0f;
            *(f32x4*)(orow + k * 256) = o;   // normal cached store (fill path)
            cnt += __popcll(__ballot(b0)) + __popcll(__ballot(b1))
                 + __popcll(__ballot(b2)) + __popcll(__ballot(b3));
        }
        if (lane0) {
            // exact: cnt/4096 is a multiple of 2^-12; partial sums dyadic <=1
            atomicAdd(&cdf[(size_t)b * PQ + p * Qq + q],
                      (float)cnt * (1.0f / (float)Ll));
        }
    }
}

// ---------------------------------------------------------------------------
// Fallback fused kernel (R4 best config) if ws can't hold a[]: 26.2 MB.
// ---------------------------------------------------------------------------
#define FGP 10
__global__ __launch_bounds__(256) void csf_fused(
    const float* __restrict__ X,
    const float* __restrict__ proj,
    const float* __restrict__ mn,
    const float* __restrict__ mx,
    float* __restrict__ cdf,
    float* __restrict__ set_out) {
    const int lt  = blockIdx.x;                 // 0..3
    const int pg  = blockIdx.y;                 // 0..9
    const int b   = blockIdx.z;                 // 0..15
    const int tid = threadIdx.x;
    const int l0  = lt * 1024 + tid * 4;
    const int p0  = __builtin_amdgcn_readfirstlane(pg * FGP);
    const float* Xb = X + (size_t)b * Cc * Ll + l0;

    float acc[FGP][4];
#pragma unroll
    for (int i = 0; i < FGP; i++)
#pragma unroll
        for (int k = 0; k < 4; k++) acc[i][k] = 0.0f;
#pragma unroll 4
    for (int c = 0; c < Cc; c++) {
        const f32x4 x = *(const f32x4*)(Xb + (size_t)c * Ll);
#pragma unroll
        for (int i = 0; i < FGP; i++) {
            const float w = proj[(size_t)(p0 + i) * Cc + c];
            acc[i][0] = __builtin_fmaf(x.x, w, acc[i][0]);
            acc[i][1] = __builtin_fmaf(x.y, w, acc[i][1]);
            acc[i][2] = __builtin_fmaf(x.z, w, acc[i][2]);
            acc[i][3] = __builtin_fmaf(x.w, w, acc[i][3]);
        }
    }
    float fr[Qq];
#pragma unroll
    for (int q = 0; q < Qq; q++) fr[q] = __fdiv_rn((float)(q + 1), 21.0f);
    float* ob = set_out + (size_t)b * PQ * Ll + l0;
    const bool lane0 = ((tid & 63) == 0);
#pragma unroll 1
    for (int i = 0; i < FGP; i++) {
        const int p = p0 + i;
        const float mnp = mn[p], mxp = mx[p];
        const float d = __fsub_rn(mxp, mnp);
#pragma unroll
        for (int q = 0; q < Qq; q++) {
            const float thr = __fadd_rn(mnp, __fmul_rn(d, fr[q]));
            const bool b0 = acc[i][0] < thr;
            const bool b1 = acc[i][1] < thr;
            const bool b2 = acc[i][2] < thr;
            const bool b3 = acc[i][3] < thr;
            f32x4 o;
            o.x = b0 ? 1.0f : 0.0f; o.y = b1 ? 1.0f : 0.0f;
            o.z = b2 ? 1.0f : 0.0f; o.w = b3 ? 1.0f : 0.0f;
            __builtin_nontemporal_store(o, (f32x4*)(ob + (size_t)(p * Qq + q) * Ll));
            const int cnt = __popcll(__ballot(b0)) + __popcll(__ballot(b1))
                          + __popcll(__ballot(b2)) + __popcll(__ballot(b3));
            if (lane0)
                atomicAdd(&cdf[(size_t)b * PQ + p * Qq + q],
                          (float)cnt * (1.0f / (float)Ll));
        }
    }
}

// ---------------------------------------------------------------------------
extern "C" void kernel_launch(void* const* d_in, const int* in_sizes, int n_in,
                              void* d_out, int out_size, void* d_ws, size_t ws_size,
                              hipStream_t stream) {
    const float* X    = (const float*)d_in[0];   // [B,C,L]
    const float* proj = (const float*)d_in[1];   // [P,C]
    const float* mn   = (const float*)d_in[2];   // [P]
    const float* mx   = (const float*)d_in[3];   // [P]

    float* cdf     = (float*)d_out;              // [B, P*Q]
    float* set_out = cdf + (size_t)Bsz * PQ;     // [B, P*Q, L]

    // zero cdf for atomic accumulation (128 KB)
    (void)hipMemsetAsync(cdf, 0, (size_t)Bsz * PQ * sizeof(float), stream);

    const size_t a_bytes = (size_t)Bsz * Pp * Ll * sizeof(float);  // 26.2 MB
    if (ws_size >= a_bytes) {
        float* a_buf = (float*)d_ws;
        csf_proj<<<dim3(4, 4, Bsz), 256, 0, stream>>>(X, proj, a_buf);
        csf_expand<<<dim3(Pp, Bsz), 256, 0, stream>>>(a_buf, mn, mx, cdf, set_out);
    } else {
        csf_fused<<<dim3(4, FGP, Bsz), 256, 0, stream>>>(X, proj, mn, mx, cdf, set_out);
    }
}

// Round 8
// 743.344 us; speedup vs baseline: 1.1431x; 1.1431x over previous
//
#include <hip/hip_runtime.h>

// Problem constants (from reference)
#define Bsz 16
#define Cc  256
#define Ll  4096
#define Pp  100
#define Qq  20
#define PQ  (Pp * Qq)     // 2000

typedef float f32x4 __attribute__((ext_vector_type(4)));

// ---------------------------------------------------------------------------
// NUMERICS CONTRACT (bit-exact vs numpy fp32 reference, validated R2/R4-R7):
//   a[b,p,l]: chain c=0..255 of a = fmaf(X[b,c,l], proj[p,c], a)      [fp32]
//   thr[p,q] = fadd(mn, fmul(fsub(mx,mn), fdiv(q+1, 21)))             [fp32,
//              separate roundings, no contraction]
//   set = (a < thr); cdf = popcount/4096 (exact dyadic fp32 atomics)
//
// R8: clean re-test of the split (R7 was confounded by K1 unroll-8 VGPR
// spills). K1 = R6-proven GEMM shape (unroll 4, shared l-tile across waves,
// X read once) + in-register cdf. K2 = fill-clone: pure linear grid-stride
// writer, structurally identical to the 6.26 TB/s fillBufferAligned.
// ---------------------------------------------------------------------------

// K1: grid (16 lt, 16 b), block 256 = 4 waves. Wave wv owns p in [25wv,+25)
// over the SAME 256-l tile (lane = 4 consecutive l) -> all waves load the same
// X rows (L1 broadcast, X read ONCE from HBM = 64 MB). Writes a[b][p][l] and
// accumulates cdf via ballots on the register accumulators.
#define PPW 25
__global__ __launch_bounds__(256) void csf_proj_cdf(
    const float* __restrict__ X,
    const float* __restrict__ proj,
    const float* __restrict__ mn,
    const float* __restrict__ mx,
    float* __restrict__ a_out,     // ws: [B][P][L]
    float* __restrict__ cdf) {     // d_out, zeroed before launch
    const int lt   = blockIdx.x;                // 0..15
    const int b    = blockIdx.y;                // 0..15
    const int tid  = threadIdx.x;
    const int lane = tid & 63;
    const int p0   = __builtin_amdgcn_readfirstlane((tid >> 6) * PPW);
    const int l0   = lt * 256 + lane * 4;

    const float* Xb = X + (size_t)b * Cc * Ll + l0;   // c-th element at +c*Ll
    const float* pj = proj + (size_t)p0 * Cc;         // wave-uniform rows

    float acc[PPW][4];
#pragma unroll
    for (int i = 0; i < PPW; i++)
#pragma unroll
        for (int k = 0; k < 4; k++) acc[i][k] = 0.0f;

    // fp32 FMA chains, c strictly ascending per accumulator (numpy order).
#pragma unroll 4
    for (int c = 0; c < Cc; c++) {
        const f32x4 x = *(const f32x4*)(Xb + (size_t)c * Ll);
#pragma unroll
        for (int i = 0; i < PPW; i++) {
            const float w = pj[(size_t)i * Cc + c];
            acc[i][0] = __builtin_fmaf(x.x, w, acc[i][0]);
            acc[i][1] = __builtin_fmaf(x.y, w, acc[i][1]);
            acc[i][2] = __builtin_fmaf(x.z, w, acc[i][2]);
            acc[i][3] = __builtin_fmaf(x.w, w, acc[i][3]);
        }
    }

    // store a (cached: K2 re-reads it through L2/L3 soon)
    float* ao = a_out + ((size_t)b * Pp + p0) * Ll + l0;
#pragma unroll
    for (int i = 0; i < PPW; i++) {
        f32x4 v;
        v.x = acc[i][0]; v.y = acc[i][1]; v.z = acc[i][2]; v.w = acc[i][3];
        *(f32x4*)(ao + (size_t)i * Ll) = v;
    }

    // cdf from register accumulators (exact dyadic counts)
    float fr[Qq];
#pragma unroll
    for (int q = 0; q < Qq; q++) fr[q] = __fdiv_rn((float)(q + 1), 21.0f);
    const bool lane0 = (lane == 0);
#pragma unroll 1
    for (int i = 0; i < PPW; i++) {
        const int p = p0 + i;
        const float mnp = mn[p];
        const float mxp = mx[p];
        const float d = __fsub_rn(mxp, mnp);          // fl(mx-mn)
#pragma unroll 1
        for (int q = 0; q < Qq; q++) {
            const float thr = __fadd_rn(mnp, __fmul_rn(d, fr[q]));
            const int cnt = __popcll(__ballot(acc[i][0] < thr))
                          + __popcll(__ballot(acc[i][1] < thr))
                          + __popcll(__ballot(acc[i][2] < thr))
                          + __popcll(__ballot(acc[i][3] < thr));
            if (lane0)
                atomicAdd(&cdf[(size_t)b * PQ + p * Qq + q],
                          (float)cnt * (1.0f / (float)Ll));
        }
    }
}

// K2: fill-clone. Grid-stride over the 32,768,000 f32x4 chunks of set_out;
// consecutive threads -> consecutive 16 B -> 1 KB contiguous per wave-store,
// grid sweeps the buffer linearly (identical pattern to fillBufferAligned).
#define NCHUNK (Bsz * PQ * (Ll / 4))   // 32,768,000
__global__ __launch_bounds__(256) void csf_expand(
    const float* __restrict__ a_in,
    const float* __restrict__ mn,
    const float* __restrict__ mx,
    float* __restrict__ set_out) {
    const unsigned T = gridDim.x * 256u;
    for (unsigned idx = blockIdx.x * 256u + threadIdx.x; idx < (unsigned)NCHUNK;
         idx += T) {
        const unsigned row = idx >> 10;           // (b*PQ + p*Q + q)
        const unsigned lc  = (idx & 1023u) << 2;  // l offset (floats)
        const unsigned b   = row / (unsigned)PQ;
        const unsigned pq  = row - b * (unsigned)PQ;
        const unsigned p   = pq / (unsigned)Qq;
        const unsigned q   = pq - p * (unsigned)Qq;

        const f32x4 a4 = *(const f32x4*)(a_in + ((size_t)b * Pp + p) * Ll + lc);

        const float mnp = mn[p];
        const float mxp = mx[p];
        const float d   = __fsub_rn(mxp, mnp);                    // fl(mx-mn)
        const float frq = __fdiv_rn((float)(q + 1u), 21.0f);      // fl((q+1)/21)
        const float thr = __fadd_rn(mnp, __fmul_rn(d, frq));      // separate rnd

        f32x4 o;
        o.x = (a4.x < thr) ? 1.0f : 0.0f;
        o.y = (a4.y < thr) ? 1.0f : 0.0f;
        o.z = (a4.z < thr) ? 1.0f : 0.0f;
        o.w = (a4.w < thr) ? 1.0f : 0.0f;
        *(f32x4*)(set_out + ((size_t)idx << 2)) = o;   // cached linear stream
    }
}

// ---------------------------------------------------------------------------
// Fallback fused kernel (R4 config, NT stores) if ws can't hold a[] (26.2 MB).
// ---------------------------------------------------------------------------
#define FGP 10
__global__ __launch_bounds__(256) void csf_fused(
    const float* __restrict__ X,
    const float* __restrict__ proj,
    const float* __restrict__ mn,
    const float* __restrict__ mx,
    float* __restrict__ cdf,
    float* __restrict__ set_out) {
    const int lt  = blockIdx.x;                 // 0..3
    const int pg  = blockIdx.y;                 // 0..9
    const int b   = blockIdx.z;                 // 0..15
    const int tid = threadIdx.x;
    const int l0  = lt * 1024 + tid * 4;
    const int p0  = __builtin_amdgcn_readfirstlane(pg * FGP);
    const float* Xb = X + (size_t)b * Cc * Ll + l0;

    float acc[FGP][4];
#pragma unroll
    for (int i = 0; i < FGP; i++)
#pragma unroll
        for (int k = 0; k < 4; k++) acc[i][k] = 0.0f;
#pragma unroll 4
    for (int c = 0; c < Cc; c++) {
        const f32x4 x = *(const f32x4*)(Xb + (size_t)c * Ll);
#pragma unroll
        for (int i = 0; i < FGP; i++) {
            const float w = proj[(size_t)(p0 + i) * Cc + c];
            acc[i][0] = __builtin_fmaf(x.x, w, acc[i][0]);
            acc[i][1] = __builtin_fmaf(x.y, w, acc[i][1]);
            acc[i][2] = __builtin_fmaf(x.z, w, acc[i][2]);
            acc[i][3] = __builtin_fmaf(x.w, w, acc[i][3]);
        }
    }
    float fr[Qq];
#pragma unroll
    for (int q = 0; q < Qq; q++) fr[q] = __fdiv_rn((float)(q + 1), 21.0f);
    float* ob = set_out + (size_t)b * PQ * Ll + l0;
    const bool lane0 = ((tid & 63) == 0);
#pragma unroll 1
    for (int i = 0; i < FGP; i++) {
        const int p = p0 + i;
        const float mnp = mn[p], mxp = mx[p];
        const float d = __fsub_rn(mxp, mnp);
#pragma unroll
        for (int q = 0; q < Qq; q++) {
            const float thr = __fadd_rn(mnp, __fmul_rn(d, fr[q]));
            const bool b0 = acc[i][0] < thr;
            const bool b1 = acc[i][1] < thr;
            const bool b2 = acc[i][2] < thr;
            const bool b3 = acc[i][3] < thr;
            f32x4 o;
            o.x = b0 ? 1.0f : 0.0f; o.y = b1 ? 1.0f : 0.0f;
            o.z = b2 ? 1.0f : 0.0f; o.w = b3 ? 1.0f : 0.0f;
            __builtin_nontemporal_store(o, (f32x4*)(ob + (size_t)(p * Qq + q) * Ll));
            const int cnt = __popcll(__ballot(b0)) + __popcll(__ballot(b1))
                          + __popcll(__ballot(b2)) + __popcll(__ballot(b3));
            if (lane0)
                atomicAdd(&cdf[(size_t)b * PQ + p * Qq + q],
                          (float)cnt * (1.0f / (float)Ll));
        }
    }
}

// ---------------------------------------------------------------------------
extern "C" void kernel_launch(void* const* d_in, const int* in_sizes, int n_in,
                              void* d_out, int out_size, void* d_ws, size_t ws_size,
                              hipStream_t stream) {
    const float* X    = (const float*)d_in[0];   // [B,C,L]
    const float* proj = (const float*)d_in[1];   // [P,C]
    const float* mn   = (const float*)d_in[2];   // [P]
    const float* mx   = (const float*)d_in[3];   // [P]

    float* cdf     = (float*)d_out;              // [B, P*Q]
    float* set_out = cdf + (size_t)Bsz * PQ;     // [B, P*Q, L]

    // zero cdf for atomic accumulation (128 KB)
    (void)hipMemsetAsync(cdf, 0, (size_t)Bsz * PQ * sizeof(float), stream);

    const size_t a_bytes = (size_t)Bsz * Pp * Ll * sizeof(float);  // 26.2 MB
    if (ws_size >= a_bytes) {
        float* a_buf = (float*)d_ws;
        csf_proj_cdf<<<dim3(16, Bsz), 256, 0, stream>>>(X, proj, mn, mx, a_buf, cdf);
        csf_expand<<<2048, 256, 0, stream>>>(a_buf, mn, mx, set_out);
    } else {
        csf_fused<<<dim3(4, FGP, Bsz), 256, 0, stream>>>(X, proj, mn, mx, cdf, set_out);
    }
}

// Round 9
// 620.748 us; speedup vs baseline: 1.3688x; 1.1975x over previous
//
#include <hip/hip_runtime.h>

// Problem constants (from reference)
#define Bsz 16
#define Cc  256
#define Ll  4096
#define Pp  100
#define Qq  20
#define PQ  (Pp * Qq)     // 2000

// R9: R4-champion fused structure, one variable changed: GP 10 -> 20
// (X re-read x10 -> x5), via 128-thread blocks (2 waves) over 512-l tiles.
// Grid (8 lt, 5 pg, 16 b) = 640 blocks = 2.5/CU (same balance as R4).
// Per (p,q) row a block writes 2 KB contiguous (2 waves x 1 KB), NT.
#define LTILE 512
#define NLT   (Ll / LTILE)   // 8
#define GP    20
#define NPG   (Pp / GP)      // 5

typedef float f32x4 __attribute__((ext_vector_type(4)));

// ---------------------------------------------------------------------------
// NUMERICS CONTRACT (bit-exact vs numpy fp32 reference, validated R2/R4-R8):
//   a[b,p,l]: chain c=0..255 of a = fmaf(X[b,c,l], proj[p,c], a)      [fp32]
//   thr[p,q] = fadd(mn, fmul(fsub(mx,mn), fdiv(q+1, 21)))             [fp32,
//              separate roundings, no contraction]
//   set = (a < thr); cdf = popcount/4096 (exact dyadic fp32 atomics)
// ---------------------------------------------------------------------------
__global__ __launch_bounds__(128) void csf_main(
    const float* __restrict__ X,
    const float* __restrict__ proj,
    const float* __restrict__ mn,
    const float* __restrict__ mx,
    float* __restrict__ cdf,       // d_out[0 .. B*P*Q), zeroed before launch
    float* __restrict__ set_out) { // d_out + B*P*Q, [B][P*Q][L]
    const int lt  = blockIdx.x;                 // 0..7
    const int pg  = blockIdx.y;                 // 0..4
    const int b   = blockIdx.z;                 // 0..15
    const int tid = threadIdx.x;                // 0..127
    const int l0  = lt * LTILE + tid * 4;       // 4 consecutive l per lane
    const int p0  = pg * GP;                    // block-uniform (SGPR)

    const float* Xb = X + (size_t)b * Cc * Ll + l0;  // c-th element at +c*Ll

    float acc[GP][4];
#pragma unroll
    for (int i = 0; i < GP; i++)
#pragma unroll
        for (int k = 0; k < 4; k++) acc[i][k] = 0.0f;

    // fp32 FMA chains, c strictly ascending per accumulator (numpy order).
    // proj rows are block-uniform -> scalar loads; x is a 16 B coalesced load.
#pragma unroll 4
    for (int c = 0; c < Cc; c++) {
        const f32x4 x = *(const f32x4*)(Xb + (size_t)c * Ll);
#pragma unroll
        for (int i = 0; i < GP; i++) {
            const float w = proj[(size_t)(p0 + i) * Cc + c];
            acc[i][0] = __builtin_fmaf(x.x, w, acc[i][0]);
            acc[i][1] = __builtin_fmaf(x.y, w, acc[i][1]);
            acc[i][2] = __builtin_fmaf(x.z, w, acc[i][2]);
            acc[i][3] = __builtin_fmaf(x.w, w, acc[i][3]);
        }
    }

    // fracs: fl((q+1)/21), IEEE division — same as np.arange/np.float32(21)
    float fr[Qq];
#pragma unroll
    for (int q = 0; q < Qq; q++) fr[q] = __fdiv_rn((float)(q + 1), 21.0f);

    float* ob = set_out + (size_t)b * PQ * Ll + l0;   // + (p*Q+q)*Ll
    const bool lane0 = ((tid & 63) == 0);

#pragma unroll 1
    for (int i = 0; i < GP; i++) {
        const int p = p0 + i;
        const float mnp = mn[p];
        const float mxp = mx[p];
        const float d = __fsub_rn(mxp, mnp);          // fl(mx-mn)
#pragma unroll
        for (int q = 0; q < Qq; q++) {
            // fl(mn + fl(d*frac)) — separate roundings, no FMA contraction
            const float thr = __fadd_rn(mnp, __fmul_rn(d, fr[q]));
            const bool b0 = acc[i][0] < thr;
            const bool b1 = acc[i][1] < thr;
            const bool b2 = acc[i][2] < thr;
            const bool b3 = acc[i][3] < thr;
            f32x4 o;
            o.x = b0 ? 1.0f : 0.0f;
            o.y = b1 ? 1.0f : 0.0f;
            o.z = b2 ? 1.0f : 0.0f;
            o.w = b3 ? 1.0f : 0.0f;
            // NT stream: champion config (R4 268 vs R5 cached 289)
            __builtin_nontemporal_store(o, (f32x4*)(ob + (size_t)(p * Qq + q) * Ll));
            // per-wave count (each wave covers 256 of this block's 512 l's)
            const int cnt = __popcll(__ballot(b0)) + __popcll(__ballot(b1))
                          + __popcll(__ballot(b2)) + __popcll(__ballot(b3));
            if (lane0) {
                // exact: every term is a multiple of 2^-12; sums dyadic <= 1
                atomicAdd(&cdf[(size_t)b * PQ + p * Qq + q],
                          (float)cnt * (1.0f / (float)Ll));
            }
        }
    }
}

// ---------------------------------------------------------------------------
extern "C" void kernel_launch(void* const* d_in, const int* in_sizes, int n_in,
                              void* d_out, int out_size, void* d_ws, size_t ws_size,
                              hipStream_t stream) {
    const float* X    = (const float*)d_in[0];   // [B,C,L]
    const float* proj = (const float*)d_in[1];   // [P,C]
    const float* mn   = (const float*)d_in[2];   // [P]
    const float* mx   = (const float*)d_in[3];   // [P]

    float* cdf     = (float*)d_out;              // [B, P*Q]
    float* set_out = cdf + (size_t)Bsz * PQ;     // [B, P*Q, L]

    // zero cdf for atomic accumulation (128 KB)
    (void)hipMemsetAsync(cdf, 0, (size_t)Bsz * PQ * sizeof(float), stream);

    dim3 grid(NLT, NPG, Bsz);
    csf_main<<<grid, 128, 0, stream>>>(X, proj, mn, mx, cdf, set_out);
}